// Round 2
// baseline (404.599 us; speedup 1.0000x reference)
//
#include <hip/hip_runtime.h>

typedef __attribute__((ext_vector_type(8))) __bf16 bf16x8;
typedef __attribute__((ext_vector_type(4))) float f32x4;

#define GRID 1024
#define BLOCK 512
#define ITERS 8   // 4 batch rows per iter -> 32 rows per block

// swizzle for 128-col bf16 LDS tiles
__device__ __forceinline__ int swz(int row, int col) {
    return row * 128 + (col ^ ((row & 7) << 3));
}
// swizzle for 16-col bf16 LDS tiles
__device__ __forceinline__ int swz16(int row, int col) {
    return row * 16 + (col ^ ((row & 1) << 3));
}

__global__ __launch_bounds__(BLOCK, 2)
void fused_attn_kernel(const float* __restrict__ obs,
                       const float* __restrict__ W1, const float* __restrict__ b1,
                       const float* __restrict__ W2, const float* __restrict__ b2,
                       const float* __restrict__ W3, const float* __restrict__ b3,
                       const float* __restrict__ Uq, const float* __restrict__ Ur,
                       float* __restrict__ out)
{
    __shared__ __align__(16) __bf16 sW1[128 * 16];
    __shared__ __align__(16) __bf16 sW2[128 * 128];
    __shared__ __align__(16) __bf16 sW3[128 * 128];
    __shared__ __align__(16) __bf16 sX0[128 * 128];
    __shared__ __align__(16) __bf16 sX1[128 * 128];
    __shared__ __align__(16) __bf16 sA1[128 * 16];
    __shared__ float sMask[128];
    __shared__ float sB1[128], sB2[128], sB3[128];
    __shared__ float sQ2[4 * 128];                    // raw column sums (query*den)
    __shared__ __align__(16) float sVp[2 * 4 * 128];  // partial v per wc half
    __shared__ float sWgt[128];
    __shared__ float sDenR[4];

    const int tid = threadIdx.x;
    const int lane = tid & 63;
    const int wv = tid >> 6;      // wave 0..7
    const int wr = wv >> 1;       // 0..3 : 32-row group (= batch row within iter)
    const int wc = wv & 1;        // 0..1 : 64-col group
    const int l15 = lane & 15;
    const int kh = lane >> 4;     // 0..3

    // ---- stage weights once per block (bf16, swizzled) ----
    for (int i = tid; i < 128 * 16; i += BLOCK) {
        int r = i >> 4, c = i & 15;
        sW1[swz16(r, c)] = (__bf16)((c < 15) ? W1[r * 15 + c] : 0.f);
    }
    for (int i = tid; i < 128 * 128; i += BLOCK) {
        int r = i >> 7, c = i & 127;
        sW2[swz(r, c)] = (__bf16)W2[i];
        sW3[swz(r, c)] = (__bf16)W3[i];
    }
    if (tid < 128) { sB1[tid] = b1[tid]; sB2[tid] = b2[tid]; sB3[tid] = b3[tid]; }
    // stage UrT (as A: A[d][e]=Ur[e][d]) into sX0, Uq (as Bw: Bw[f][e]=Uq[e][f]) into sX1
    for (int i = tid; i < 128 * 128; i += BLOCK) {
        int e = i >> 7, x = i & 127;
        sX0[swz(x, e)] = (__bf16)Ur[i];
        sX1[swz(x, e)] = (__bf16)Uq[i];
    }
    __syncthreads();

    // ---- M = Ur^T @ Uq, kept in registers: accM[mt][nt][r] = M[d][f]
    //      d = wr*32 + mt*16 + kh*4 + r ; f = wc*64 + nt*16 + l15
    f32x4 accM[2][4];
    #pragma unroll
    for (int mt = 0; mt < 2; ++mt)
        #pragma unroll
        for (int nt = 0; nt < 4; ++nt) accM[mt][nt] = f32x4{0.f, 0.f, 0.f, 0.f};
    #pragma unroll
    for (int kk = 0; kk < 4; ++kk) {
        int kb = kk * 32 + kh * 8;
        bf16x8 a[2], b[4];
        #pragma unroll
        for (int mt = 0; mt < 2; ++mt) {
            int row = wr * 32 + mt * 16 + l15;
            a[mt] = *(const bf16x8*)&sX0[row * 128 + (kb ^ ((row & 7) << 3))];
        }
        #pragma unroll
        for (int nt = 0; nt < 4; ++nt) {
            int col = wc * 64 + nt * 16 + l15;
            b[nt] = *(const bf16x8*)&sX1[col * 128 + (kb ^ ((col & 7) << 3))];
        }
        #pragma unroll
        for (int mt = 0; mt < 2; ++mt)
            #pragma unroll
            for (int nt = 0; nt < 4; ++nt)
                accM[mt][nt] = __builtin_amdgcn_mfma_f32_16x16x32_bf16(a[mt], b[nt], accM[mt][nt], 0, 0, 0);
    }
    __syncthreads();

    for (int g = 0; g < ITERS; ++g) {
        const int row0 = blockIdx.x * (4 * ITERS) + g * 4;

        // ---- Phase B: stage feats (pad col15 to 0) + mask ----
        {
            int m = tid >> 2, f4 = tid & 3;
            int rb = row0 + (m >> 5), n = m & 31;
            f32x4 v = *(const f32x4*)&obs[rb * 576 + 32 + n * 16 + f4 * 4];
            if (f4 == 3) { sMask[m] = v.w; v.w = 0.f; }
            int c0 = f4 * 4;
            sA1[swz16(m, c0 + 0)] = (__bf16)v.x;
            sA1[swz16(m, c0 + 1)] = (__bf16)v.y;
            sA1[swz16(m, c0 + 2)] = (__bf16)v.z;
            sA1[swz16(m, c0 + 3)] = (__bf16)v.w;
        }
        __syncthreads();

        // ---- Layer 1 (plus mask-denominator reciprocal) ----
        {
            if (tid < 128) {
                float mv = sMask[tid];
                #pragma unroll
                for (int off = 16; off > 0; off >>= 1) mv += __shfl_xor(mv, off, 32);
                if ((tid & 31) == 0) sDenR[tid >> 5] = 1.f / (mv + 1e-5f);
            }
            f32x4 acc[2][4];
            #pragma unroll
            for (int mt = 0; mt < 2; ++mt)
                #pragma unroll
                for (int nt = 0; nt < 4; ++nt) acc[mt][nt] = f32x4{0.f, 0.f, 0.f, 0.f};

            bf16x8 zfrag;
            #pragma unroll
            for (int j = 0; j < 8; ++j) zfrag[j] = (__bf16)0.f;

            int c8 = (kh & 1) * 8;
            bf16x8 af[2], bfr[4];
            #pragma unroll
            for (int mt = 0; mt < 2; ++mt) {
                int row = wr * 32 + mt * 16 + l15;
                bf16x8 t = *(const bf16x8*)&sA1[row * 16 + (c8 ^ ((row & 1) << 3))];
                af[mt] = (kh < 2) ? t : zfrag;
            }
            #pragma unroll
            for (int nt = 0; nt < 4; ++nt) {
                int col = wc * 64 + nt * 16 + l15;
                bf16x8 t = *(const bf16x8*)&sW1[col * 16 + (c8 ^ ((col & 1) << 3))];
                bfr[nt] = (kh < 2) ? t : zfrag;
            }
            #pragma unroll
            for (int mt = 0; mt < 2; ++mt)
                #pragma unroll
                for (int nt = 0; nt < 4; ++nt)
                    acc[mt][nt] = __builtin_amdgcn_mfma_f32_16x16x32_bf16(af[mt], bfr[nt], acc[mt][nt], 0, 0, 0);

            #pragma unroll
            for (int mt = 0; mt < 2; ++mt) {
                int rbase = wr * 32 + mt * 16 + kh * 4;
                #pragma unroll
                for (int nt = 0; nt < 4; ++nt) {
                    int col = wc * 64 + nt * 16 + l15;
                    float bb = sB1[col];
                    #pragma unroll
                    for (int r = 0; r < 4; ++r) {
                        float hv = fmaxf(acc[mt][nt][r] + bb, 0.f);
                        sX0[swz(rbase + r, col)] = (__bf16)hv;
                    }
                }
            }
        }
        __syncthreads();

        // ---- Layers 2 & 3 ----
        auto gemm128 = [&](const __bf16* A, const __bf16* Bw, const float* bias,
                           bool do_relu, bool do_mask_colsum, __bf16* Out) {
            f32x4 acc[2][4];
            #pragma unroll
            for (int mt = 0; mt < 2; ++mt)
                #pragma unroll
                for (int nt = 0; nt < 4; ++nt) acc[mt][nt] = f32x4{0.f, 0.f, 0.f, 0.f};

            #pragma unroll
            for (int kk = 0; kk < 4; ++kk) {
                int kb = kk * 32 + kh * 8;
                bf16x8 a[2], b[4];
                #pragma unroll
                for (int mt = 0; mt < 2; ++mt) {
                    int row = wr * 32 + mt * 16 + l15;
                    a[mt] = *(const bf16x8*)&A[row * 128 + (kb ^ ((row & 7) << 3))];
                }
                #pragma unroll
                for (int nt = 0; nt < 4; ++nt) {
                    int col = wc * 64 + nt * 16 + l15;
                    b[nt] = *(const bf16x8*)&Bw[col * 128 + (kb ^ ((col & 7) << 3))];
                }
                #pragma unroll
                for (int mt = 0; mt < 2; ++mt)
                    #pragma unroll
                    for (int nt = 0; nt < 4; ++nt)
                        acc[mt][nt] = __builtin_amdgcn_mfma_f32_16x16x32_bf16(a[mt], b[nt], acc[mt][nt], 0, 0, 0);
            }
            float cs[4] = {0.f, 0.f, 0.f, 0.f};
            #pragma unroll
            for (int mt = 0; mt < 2; ++mt) {
                int rbase = wr * 32 + mt * 16 + kh * 4;
                #pragma unroll
                for (int nt = 0; nt < 4; ++nt) {
                    int col = wc * 64 + nt * 16 + l15;
                    float bb = bias[col];
                    #pragma unroll
                    for (int r = 0; r < 4; ++r) {
                        float hv = acc[mt][nt][r] + bb;
                        if (do_relu) hv = fmaxf(hv, 0.f);
                        if (do_mask_colsum) hv *= sMask[rbase + r];
                        cs[nt] += hv;
                        Out[swz(rbase + r, col)] = (__bf16)hv;
                    }
                }
            }
            if (do_mask_colsum) {   // fused column-sum -> raw query
                #pragma unroll
                for (int nt = 0; nt < 4; ++nt) {
                    float c = cs[nt];
                    c += __shfl_xor(c, 16);
                    c += __shfl_xor(c, 32);
                    if (kh == 0) sQ2[wr * 128 + wc * 64 + nt * 16 + l15] = c;
                }
            }
        };
        gemm128(sX0, sW2, sB2, true, false, sX1);   // h2
        __syncthreads();
        gemm128(sX1, sW3, sB3, false, true, sX0);   // x_real + colsum->sQ2
        __syncthreads();

        // ---- Phase G: v = M @ (query/den) using in-register M ----
        {
            #pragma unroll
            for (int b = 0; b < 4; ++b) {
                float rd = sDenR[b];
                float qv[4];
                #pragma unroll
                for (int nt = 0; nt < 4; ++nt)
                    qv[nt] = sQ2[b * 128 + wc * 64 + nt * 16 + l15] * rd;
                #pragma unroll
                for (int mt = 0; mt < 2; ++mt) {
                    #pragma unroll
                    for (int r = 0; r < 4; ++r) {
                        float p = accM[mt][0][r] * qv[0] + accM[mt][1][r] * qv[1]
                                + accM[mt][2][r] * qv[2] + accM[mt][3][r] * qv[3];
                        p += __shfl_xor(p, 1);
                        p += __shfl_xor(p, 2);
                        p += __shfl_xor(p, 4);
                        p += __shfl_xor(p, 8);
                        if (l15 == 0)
                            sVp[wc * 512 + b * 128 + wr * 32 + mt * 16 + kh * 4 + r] = p;
                    }
                }
            }
        }
        __syncthreads();

        // ---- Phase H: logits + softmax (tid<128) ∥ aux passthrough (tid 128..383) ----
        if (tid < 128) {
            int m = tid, b = m >> 5;
            float a = 0.f;
            #pragma unroll
            for (int c8 = 0; c8 < 16; ++c8) {
                bf16x8 xv = *(const bf16x8*)&sX0[m * 128 + ((c8 * 8) ^ ((m & 7) << 3))];
                f32x4 v0 = *(const f32x4*)&sVp[b * 128 + c8 * 8];
                f32x4 v1 = *(const f32x4*)&sVp[b * 128 + c8 * 8 + 4];
                f32x4 w0 = *(const f32x4*)&sVp[512 + b * 128 + c8 * 8];
                f32x4 w1 = *(const f32x4*)&sVp[512 + b * 128 + c8 * 8 + 4];
                a += (float)xv[0] * (v0.x + w0.x) + (float)xv[1] * (v0.y + w0.y)
                   + (float)xv[2] * (v0.z + w0.z) + (float)xv[3] * (v0.w + w0.w)
                   + (float)xv[4] * (v1.x + w1.x) + (float)xv[5] * (v1.y + w1.y)
                   + (float)xv[6] * (v1.z + w1.z) + (float)xv[7] * (v1.w + w1.w);
            }
            float logit = a + (1.0f - sMask[m]) * (-1e9f);
            float mx = logit;
            #pragma unroll
            for (int off = 16; off > 0; off >>= 1) mx = fmaxf(mx, __shfl_xor(mx, off, 32));
            float ex = __expf(logit - mx);
            float sm = ex;
            #pragma unroll
            for (int off = 16; off > 0; off >>= 1) sm += __shfl_xor(sm, off, 32);
            sWgt[m] = ex / sm;
        } else if (tid < 384) {
            int t = tid - 128;
            int r = t >> 6, j = t & 63;
            out[(row0 + r) * 192 + j] = (j < 32) ? obs[(row0 + r) * 576 + j]
                                                 : obs[(row0 + r) * 576 + 512 + j];
        }
        __syncthreads();

        // ---- Phase I: out_att[e] = sum_n w[n] * x_real[n][e] ----
        {
            int r = tid >> 7, e = tid & 127;
            float a = 0.f;
            #pragma unroll 8
            for (int i = 0; i < 32; ++i)
                a += sWgt[r * 32 + i] * (float)sX0[swz(r * 32 + i, e)];
            out[(row0 + r) * 192 + 64 + e] = a;
        }
        __syncthreads();   // protect LDS reuse before next iteration
    }
}

extern "C" void kernel_launch(void* const* d_in, const int* in_sizes, int n_in,
                              void* d_out, int out_size, void* d_ws, size_t ws_size,
                              hipStream_t stream) {
    const float* obs = (const float*)d_in[0];
    const float* W1  = (const float*)d_in[1];
    const float* b1  = (const float*)d_in[2];
    const float* W2  = (const float*)d_in[3];
    const float* b2  = (const float*)d_in[4];
    const float* W3  = (const float*)d_in[5];
    const float* b3  = (const float*)d_in[6];
    const float* Uq  = (const float*)d_in[7];
    const float* Ur  = (const float*)d_in[8];
    float* out = (float*)d_out;

    fused_attn_kernel<<<dim3(GRID), dim3(BLOCK), 0, stream>>>(
        obs, W1, b1, W2, b2, W3, b3, Uq, Ur, out);
}